// Round 5
// baseline (396.814 us; speedup 1.0000x reference)
//
#include <hip/hip_runtime.h>
#include <cstdint>
#include <cstddef>

#define DEVI __device__ __forceinline__

typedef __bf16 bf16x8 __attribute__((ext_vector_type(8)));
typedef float floatx4 __attribute__((ext_vector_type(4)));
typedef unsigned short us4v __attribute__((ext_vector_type(4)));
typedef unsigned short us8 __attribute__((ext_vector_type(8)));

static_assert(sizeof(bf16x8) == 16, "bf16x8 must be 16B");
static_assert(sizeof(us8) == 16, "us8 must be 16B");

// ---------------- helpers ----------------

#if __has_builtin(__builtin_amdgcn_cvt_pk_bf16_f32)
DEVI unsigned short f2bf(float f) {
  typedef __bf16 bf16x2 __attribute__((ext_vector_type(2)));
  union { bf16x2 v; unsigned short u[2]; } c;
  c.v = __builtin_amdgcn_cvt_pk_bf16_f32(f, 0.f);
  return c.u[0];
}
#else
DEVI unsigned short f2bf(float f) {
  unsigned int u = __float_as_uint(f);
  u += 0x7fffu + ((u >> 16) & 1u);   // RNE
  return (unsigned short)(u >> 16);
}
#endif

DEVI float exp2c(float x) {
#if __has_builtin(__builtin_amdgcn_exp2f)
  return __builtin_amdgcn_exp2f(x);
#else
  return exp2f(x);
#endif
}

DEVI bf16x8 ld8(const unsigned short* p) { return *(const bf16x8*)p; }

typedef const __attribute__((address_space(1))) void* gas_ptr;
typedef __attribute__((address_space(3))) void* las_ptr;

DEVI void gld16(const void* g, void* l) {
  __builtin_amdgcn_global_load_lds((gas_ptr)g, (las_ptr)l, 16, 0, 0);
}

#define WAIT_LGKM0() __builtin_amdgcn_s_waitcnt(0xc07f)   // lgkmcnt(0) only
#define WAIT_VM12()  __builtin_amdgcn_s_waitcnt(0x0f7c)   // vmcnt(12) only
#define WAIT_VM0()   __builtin_amdgcn_s_waitcnt(0x0f70)   // vmcnt(0) only
#define SB()         __builtin_amdgcn_sched_barrier(0)

// ---- hand-rolled grid barrier (agent scope, cross-XCD coherent) ----
// Requires all 512 blocks co-resident: __launch_bounds__(256,2) + 66.5KB LDS
// -> exactly 2 blocks/CU on 256 CUs. Counter zeroed by stream-ordered memset;
// monotonic targets (no reset between phases).
DEVI void grid_bar(unsigned int* cnt, unsigned int target, int tid) {
  __syncthreads();
  if (tid == 0) {
    __threadfence();   // flush this block's global writes (wbl2)
    __hip_atomic_fetch_add(cnt, 1u, __ATOMIC_ACQ_REL, __HIP_MEMORY_SCOPE_AGENT);
    while (__hip_atomic_load(cnt, __ATOMIC_ACQUIRE, __HIP_MEMORY_SCOPE_AGENT) < target)
      __builtin_amdgcn_s_sleep(16);
  }
  __syncthreads();     // all waves of block see post-inv caches
}

// ================= fused persistent kernel (plain launch + own barrier) =================
// grid = 512 blocks x 256 threads, 2 blocks/CU (LDS 66.5 KB).
// Phase 0: prep (mask pack / cvt / weight transpose), 10624 units grid-strided.
// Phase 1: QKV GEMM, 768 64x128 tiles grid-strided.
// Phase 2: flash attention, 512 units (identity map) -- pins grid shape.
// Phase 3: out GEMM, 256 64x128 tiles on blocks 0..255.
__global__ __launch_bounds__(256, 2) void mega_k(
    const float* __restrict__ nodes, const void* __restrict__ mask,
    const float* __restrict__ wq, const float* __restrict__ wkv,
    const float* __restrict__ wo,
    const float* __restrict__ bq, const float* __restrict__ bkv,
    const float* __restrict__ bo,
    unsigned short* __restrict__ XB, unsigned short* __restrict__ WQKVT,
    unsigned short* __restrict__ WOT, unsigned int* __restrict__ pm,
    unsigned short* __restrict__ Qm, unsigned short* __restrict__ Km,
    unsigned short* __restrict__ VTm, unsigned short* __restrict__ AOm,
    float* __restrict__ out, unsigned int* __restrict__ gcnt) {
  __shared__ alignas(16) char smU[66560];    // 64 KB main + 1 KB aux + pad
  const int blk = blockIdx.x;
  const int tid = threadIdx.x;
  const int wave = tid >> 6, lane = tid & 63, quad = lane >> 4, l16 = lane & 15;

  // ---------------- phase 0: prep ----------------
  {
    int* modeP = (int*)(smU + 65536);
    unsigned short* t2 = (unsigned short*)smU;   // 8 KB
    for (int bid = blk; bid < 10624; bid += 512) {
      __syncthreads();                           // protect LDS reuse across units
      if (bid < 8192) {
        // ---- mask pack: thread handles 4 elems; 8 threads -> one 32-bit word ----
        const unsigned int* md = (const unsigned int*)mask;
        unsigned int probe = md[tid];
        bool odd = (probe > 1u && probe != 0x3f800000u);
        if (tid == 0) *modeP = 0;
        __syncthreads();
        if (odd) atomicOr(modeP, 1);
        __syncthreads();
        int byteMode = *modeP;
        int t = bid * 256 + tid;
        unsigned int n;
        if (byteMode) {
          unsigned int x = md[t];
          n = ((x & 0xffu) ? 1u : 0u) | ((x & 0xff00u) ? 2u : 0u) |
              ((x & 0xff0000u) ? 4u : 0u) | ((x >> 24) ? 8u : 0u);
        } else {
          uint4 v = ((const uint4*)mask)[t];
          n = (v.x ? 1u : 0u) | (v.y ? 2u : 0u) | (v.z ? 4u : 0u) | (v.w ? 8u : 0u);
        }
        unsigned int w = n << ((lane & 7) * 4);
        w |= __shfl_xor(w, 1);
        w |= __shfl_xor(w, 2);
        w |= __shfl_xor(w, 4);
        if ((lane & 7) == 0) pm[t >> 3] = w;
      } else if (bid < 10240) {
        // ---- nodes fp32 -> bf16 ----
        int i = (bid - 8192) * 256 + tid;
        float4 v = ((const float4*)nodes)[i];
        us4v o;
        o[0] = f2bf(v.x); o[1] = f2bf(v.y); o[2] = f2bf(v.z); o[3] = f2bf(v.w);
        *(us4v*)(XB + (size_t)i * 4) = o;
      } else {
        // ---- weight transpose fp32 [512][C] -> bf16 dst[(c0+c)*512+k] ----
        int tb = bid - 10240;
        int x = tb & 15, y = (tb >> 4) & 7, z = tb >> 7;
        const float* src; unsigned short* dst; int C, c0;
        bool active = true;
        if (z == 0)      { if (x >= 8) active = false; src = wq;  dst = WQKVT; C = 512;  c0 = 0; }
        else if (z == 1) { src = wkv; dst = WQKVT; C = 1024; c0 = 512; }
        else             { if (x >= 8) active = false; src = wo;  dst = WOT;  C = 512;  c0 = 0; }
        if (active) {                            // block-uniform condition
          const int t = tid;
          const int ct = x * 64, rt = y * 64;
          for (int p = 0; p < 4; p++) {
            int kl = p * 16 + (t >> 4);
            int cc = (t & 15) * 4;
            float4 v = *(const float4*)&src[(size_t)(rt + kl) * C + ct + cc];
            float f[4] = {v.x, v.y, v.z, v.w};
            for (int i = 0; i < 4; i++) {
              int c = cc + i;
              t2[c * 64 + (kl ^ (c & 56))] = f2bf(f[i]);
            }
          }
          __syncthreads();
          for (int p = 0; p < 2; p++) {
            int c = p * 32 + (t >> 3);
            int kc = (t & 7) * 8;
            us8 v = *(const us8*)&t2[c * 64 + (kc ^ (c & 56))];
            *(us8*)&dst[(size_t)(c0 + ct + c) * 512 + rt + kc] = v;
          }
        }
      }
    }
  }
  grid_bar(gcnt, 512, tid);

  // ---------------- phase 1: QKV GEMM (64x128 tiles, 768 grid-strided) ----------------
  {
    unsigned short* smem = (unsigned short*)smU;   // 16 KB
    unsigned short* sA = smem;
    unsigned short* sB = smem + 2048;
    const int wm = wave >> 1, wn = wave & 1;
    const int arow = lane >> 2;
    const int ag = lane & 3;
    for (int t = blk; t < 768; t += 512) {
      const int bm = t & 63, bn = t >> 6;
      floatx4 acc[2][4] = {};
      for (int kt = 0; kt < 16; kt++) {
        __syncthreads();
        {
          int rowA = wave * 16 + arow;
          int gA = ag ^ (rowA & 3);
          gld16(&XB[(size_t)(bm * 64 + rowA) * 512 + kt * 32 + gA * 8], &sA[(wave * 16) * 32]);
          for (int p = 0; p < 2; p++) {
            int rowB = p * 64 + wave * 16 + arow;
            int gB = ag ^ (rowB & 3);
            gld16(&WQKVT[(size_t)(bn * 128 + rowB) * 512 + kt * 32 + gB * 8],
                  &sB[(p * 64 + wave * 16) * 32]);
          }
        }
        __syncthreads();
        bf16x8 aF[2], bF[4];
        int swz = (quad ^ (l16 & 3)) * 8;
        for (int i = 0; i < 2; i++) aF[i] = ld8(&sA[(wm * 32 + i * 16 + l16) * 32 + swz]);
        for (int j = 0; j < 4; j++) bF[j] = ld8(&sB[(wn * 64 + j * 16 + l16) * 32 + swz]);
        for (int i = 0; i < 2; i++)
          for (int j = 0; j < 4; j++)
            acc[i][j] = __builtin_amdgcn_mfma_f32_16x16x32_bf16(aF[i], bF[j], acc[i][j], 0, 0, 0);
      }

      const int sec = bn * 2 + wn;               // 0..23: Q heads 0-7, K 8-15, V 16-23
      float bias[4];
      float scale = 1.0f;
      if (sec < 8) {
        for (int j = 0; j < 4; j++) bias[j] = bq[sec * 64 + j * 16 + l16];
        scale = 0.18033688011112042f;            // 0.125 * log2(e)
      } else {
        for (int j = 0; j < 4; j++) bias[j] = bkv[(sec - 8) * 64 + j * 16 + l16];
      }
      const int gr0 = bm * 64 + wm * 32;
      const int b = gr0 >> 11, n0 = gr0 & 2047;
      unsigned short* pw = smem + wave * 2048;
      __syncthreads();
      if (sec < 16) {
        for (int i = 0; i < 2; i++)
          for (int j = 0; j < 4; j++) {
            int cg2 = j * 2 + (l16 >> 3), ci = l16 & 7;
            for (int r = 0; r < 4; r++) {
              int row = i * 16 + quad * 4 + r;
              pw[row * 64 + ((cg2 ^ (row & 7)) * 8) + ci] = f2bf((acc[i][j][r] + bias[j]) * scale);
            }
          }
        WAIT_LGKM0();
        unsigned short* dst = (sec < 8) ? Qm + ((size_t)(b * 8 + sec) * 2048 + n0) * 64
                                        : Km + ((size_t)(b * 8 + sec - 8) * 2048 + n0) * 64;
        for (int p = 0; p < 4; p++) {
          int row = p * 8 + (lane >> 3);
          int c8 = lane & 7;
          us8 v = *(const us8*)&pw[row * 64 + ((c8 ^ (row & 7)) * 8)];
          *(us8*)&dst[(size_t)row * 64 + c8 * 8] = v;
        }
      } else {
        // V: [64 d][32 n] s-permuted; local n = i*16 + quad*4 + r -> s = quad*8 + i*4 + r
        for (int i = 0; i < 2; i++)
          for (int j = 0; j < 4; j++) {
            int d = j * 16 + l16;
            us4v tv;
            for (int r = 0; r < 4; r++) tv[r] = f2bf(acc[i][j][r] + bias[j]);
            *(us4v*)&pw[d * 32 + ((quad ^ (d & 3)) * 8) + i * 4] = tv;
          }
        WAIT_LGKM0();
        unsigned short* dst = VTm + (size_t)(b * 8 + sec - 16) * 64 * 2048 + n0;
        for (int p = 0; p < 4; p++) {
          int d = p * 16 + (lane >> 2);
          int c4 = lane & 3;
          us8 v = *(const us8*)&pw[d * 32 + ((c4 ^ (d & 3)) * 8)];
          *(us8*)&dst[(size_t)d * 2048 + c4 * 8] = v;
        }
      }
    }
  }
  grid_bar(gcnt, 1024, tid);

  // ---------------- phase 2: flash attention (identity map, 512 units) ----------------
  {
    // per (buf, wave): [0,2048) K tile [32 keys][64 d], [2048,4096) V tile [64 d][32 s]
    unsigned short (*kv)[4][4096] = (unsigned short (*)[4][4096])smU;   // 64 KB
    float (*lsumB)[64] = (float (*)[64])(smU + 65536);                  // 1 KB
    const int bh = blk & 15, qt = blk >> 4, b = bh >> 3, h = bh & 7;
    const int q0 = qt * 64;
    const unsigned short* Qb = Qm + (size_t)bh * 2048 * 64;
    const unsigned short* Kb = Km + (size_t)bh * 2048 * 64;
    const unsigned short* Vb = VTm + (size_t)bh * 64 * 2048;
    const unsigned int* pmB = pm + (size_t)b * 2048 * 64;

    bf16x8 qF[4][2];
#pragma unroll
    for (int qb = 0; qb < 4; qb++) {
      qF[qb][0] = ld8(&Qb[(size_t)(q0 + qb * 16 + l16) * 64 + quad * 8]);
      qF[qb][1] = ld8(&Qb[(size_t)(q0 + qb * 16 + l16) * 64 + 32 + quad * 8]);
    }

    floatx4 oacc[4][4] = {};                   // [db][qb]
    floatx4 lsacc[4] = {};                     // ones-MFMA row sums, [qb]

    union { us8 u; bf16x8 v; } onesU;
#pragma unroll
    for (int i = 0; i < 8; i++) onesU.u[i] = 0x3f80;   // bf16 1.0
    const bf16x8 onesF = onesU.v;

    const int srow = lane >> 3;                // K staging: row-in-8
    const int gK = (lane & 7) ^ srow;          // K source d-group (3-bit XOR)
    const int dV = lane >> 2;                  // V staging: d-row-in-16
    const int gV = (lane & 3) ^ (dV & 3);      // V source s-group (2-bit XOR)
    const int rsw0 = quad ^ (l16 & 7);
    const int rsw1 = (4 + quad) ^ (l16 & 7);

    unsigned short* kv0 = &kv[0][wave][0];
    unsigned short* kv1 = &kv[1][wave][0];

    struct MW { unsigned int w[4]; };
    MW mwA, mwB;

    auto prefetch = [&](int it, unsigned short* dst, MW& mw) {
      const int k0w = it * 128 + wave * 32;
#pragma unroll
      for (int qb = 0; qb < 4; qb++)
        mw.w[qb] = pmB[(size_t)(q0 + qb * 16 + l16) * 64 + it * 4 + wave];
#pragma unroll
      for (int p = 0; p < 4; p++) {
        gld16(&Kb[(size_t)(k0w + p * 8 + srow) * 64 + gK * 8], dst + p * 512);
        gld16(&Vb[(size_t)(p * 16 + dV) * 2048 + k0w + gV * 8], dst + 2048 + p * 512);
      }
    };

    auto step = [&](const unsigned short* buf, const MW& mw) {
      floatx4 st[4][2];
      __builtin_amdgcn_s_setprio(1);
#pragma unroll
      for (int k2 = 0; k2 < 2; k2++) {
        const unsigned short* kr = &buf[(k2 * 16 + l16) * 64];
        bf16x8 kf0 = ld8(kr + rsw0 * 8);
        bf16x8 kf1 = ld8(kr + rsw1 * 8);
#pragma unroll
        for (int qb = 0; qb < 4; qb++) {
          floatx4 z = {0.f, 0.f, 0.f, 0.f};
          z = __builtin_amdgcn_mfma_f32_16x16x32_bf16(kf0, qF[qb][0], z, 0, 0, 0);
          st[qb][k2] = __builtin_amdgcn_mfma_f32_16x16x32_bf16(kf1, qF[qb][1], z, 0, 0, 0);
        }
      }
      __builtin_amdgcn_s_setprio(0);
      union uB { bf16x8 v; unsigned short u[8]; } pf[4];
#pragma unroll
      for (int qb = 0; qb < 4; qb++) {
        unsigned int w = mw.w[qb];
#pragma unroll
        for (int k2 = 0; k2 < 2; k2++) {
#pragma unroll
          for (int r = 0; r < 4; r++) {
            float e = exp2c(st[qb][k2][r]);
            e = ((w >> (k2 * 16 + quad * 4 + r)) & 1u) ? e : 0.f;
            pf[qb].u[k2 * 4 + r] = f2bf(e);
          }
        }
      }
      __builtin_amdgcn_s_setprio(1);
#pragma unroll
      for (int qb = 0; qb < 4; qb++)
        lsacc[qb] = __builtin_amdgcn_mfma_f32_16x16x32_bf16(onesF, pf[qb].v, lsacc[qb], 0, 0, 0);
#pragma unroll
      for (int db = 0; db < 4; db++) {
        const int d = db * 16 + l16;
        bf16x8 va = ld8(&buf[2048 + d * 32 + ((quad ^ (d & 3)) * 8)]);
#pragma unroll
        for (int qb = 0; qb < 4; qb++)
          oacc[db][qb] =
              __builtin_amdgcn_mfma_f32_16x16x32_bf16(va, pf[qb].v, oacc[db][qb], 0, 0, 0);
      }
      __builtin_amdgcn_s_setprio(0);
    };

    SB();
    prefetch(0, kv0, mwA);
    SB();
#pragma unroll 1
    for (int i = 0; i < 8; ++i) {
      prefetch(i * 2 + 1, kv1, mwB);
      SB();
      WAIT_VM12();
      SB();
      step(kv0, mwA);
      SB();
      if (i < 7) {
        prefetch(i * 2 + 2, kv0, mwA);
        SB();
        WAIT_VM12();
        SB();
      } else {
        WAIT_VM0();
        SB();
      }
      step(kv1, mwB);
      SB();
    }

    if (quad == 0) {
#pragma unroll
      for (int qb = 0; qb < 4; qb++) lsumB[wave][qb * 16 + l16] = lsacc[qb][0];
    }
    __syncthreads();                           // all waves done with kv buffers

    float* pO = (float*)smU;                   // 64 KB = 4 regions x 16 KB
    float* myR = pO + wave * 4096;
#pragma unroll
    for (int db = 0; db < 4; db++)
#pragma unroll
      for (int qb = 0; qb < 4; qb++) {
        int q = qb * 16 + l16;
        *(floatx4*)&myR[q * 64 + (((db * 4 + quad) ^ l16) & 15) * 4] = oacc[db][qb];
      }
    __syncthreads();
    {
      int q = tid >> 2, dblk = tid & 3;
      float inv = 1.0f / (lsumB[0][q] + lsumB[1][q] + lsumB[2][q] + lsumB[3][q]);
      float o[16];
      for (int i = 0; i < 4; i++) {
        int dg = dblk * 4 + i;
        int off = q * 64 + ((dg ^ q) & 15) * 4;
        floatx4 s = *(floatx4*)&pO[off];
        s += *(floatx4*)&pO[4096 + off];
        s += *(floatx4*)&pO[8192 + off];
        s += *(floatx4*)&pO[12288 + off];
        for (int r = 0; r < 4; r++) o[i * 4 + r] = s[r] * inv;
      }
      us8 v0, v1;
      for (int i = 0; i < 8; i++) { v0[i] = f2bf(o[i]); v1[i] = f2bf(o[8 + i]); }
      unsigned short* dst = &AOm[((size_t)b * 2048 + q0 + q) * 512 + h * 64 + dblk * 16];
      *(us8*)dst = v0;
      *(us8*)(dst + 8) = v1;
    }
  }
  grid_bar(gcnt, 1536, tid);

  // ---------------- phase 3: out GEMM (64x128 tiles, blocks 0..255) ----------------
  if (blk < 256) {
    unsigned short* smem = (unsigned short*)smU;   // 12 KB
    unsigned short* sA = smem;
    unsigned short* sB = smem + 2048;
    const int wm = wave >> 1, wn = wave & 1;
    const int bm = blk & 63, bn = blk >> 6;
    floatx4 acc[2][4] = {};
    const int arow = lane >> 2;
    const int ag = lane & 3;
    for (int kt = 0; kt < 16; kt++) {
      __syncthreads();
      {
        int rowA = wave * 16 + arow;
        int gA = ag ^ (rowA & 3);
        gld16(&AOm[(size_t)(bm * 64 + rowA) * 512 + kt * 32 + gA * 8], &sA[(wave * 16) * 32]);
        for (int p = 0; p < 2; p++) {
          int rowB = p * 64 + wave * 16 + arow;
          int gB = ag ^ (rowB & 3);
          gld16(&WOT[(size_t)(bn * 128 + rowB) * 512 + kt * 32 + gB * 8],
                &sB[(p * 64 + wave * 16) * 32]);
        }
      }
      __syncthreads();
      bf16x8 aF[2], bF[4];
      int swz = (quad ^ (l16 & 3)) * 8;
      for (int i = 0; i < 2; i++) aF[i] = ld8(&sA[(wm * 32 + i * 16 + l16) * 32 + swz]);
      for (int j = 0; j < 4; j++) bF[j] = ld8(&sB[(wn * 64 + j * 16 + l16) * 32 + swz]);
      for (int i = 0; i < 2; i++)
        for (int j = 0; j < 4; j++)
          acc[i][j] = __builtin_amdgcn_mfma_f32_16x16x32_bf16(aF[i], bF[j], acc[i][j], 0, 0, 0);
    }
    for (int i = 0; i < 2; i++)
      for (int j = 0; j < 4; j++) {
        int gc = bn * 128 + wn * 64 + j * 16 + l16;
        float bb = bo[gc];
        for (int r = 0; r < 4; r++) {
          int gr = bm * 64 + wm * 32 + i * 16 + quad * 4 + r;
          out[(size_t)gr * 512 + gc] = acc[i][j][r] + bb;
        }
      }
  }
}

// ---------------- launch ----------------
extern "C" void kernel_launch(void* const* d_in, const int* in_sizes, int n_in,
                              void* d_out, int out_size, void* d_ws, size_t ws_size,
                              hipStream_t stream) {
  const float* nodes = (const float*)d_in[0];
  const void*  mask  = d_in[1];
  const float* wq    = (const float*)d_in[2];
  const float* bq    = (const float*)d_in[3];
  const float* wkv   = (const float*)d_in[4];
  const float* bkv   = (const float*)d_in[5];
  const float* wo    = (const float*)d_in[6];
  const float* bo    = (const float*)d_in[7];
  float* out = (float*)d_out;

  char* ws = (char*)d_ws;
  unsigned short* XB    = (unsigned short*)(ws + 0);          //  4 MB  bf16 nodes
  unsigned short* WQKVT = (unsigned short*)(ws + 4194304);    //  1.5MB
  unsigned short* WOT   = (unsigned short*)(ws + 5767168);    //  0.5MB
  unsigned short* Qm    = (unsigned short*)(ws + 6291456);    //  4 MB  [16][2048][64]
  unsigned short* Km    = (unsigned short*)(ws + 10485760);   //  4 MB
  unsigned short* VTm   = (unsigned short*)(ws + 18874368);   //  4 MB  [16][64][2048] s-perm
  unsigned short* AOm   = (unsigned short*)(ws + 23068672);   //  4 MB  [4096][512]
  unsigned int*   PM    = (unsigned int*)(ws + 27262976);     //  1 MB  packed mask
  unsigned int*   CNT   = (unsigned int*)(ws + 28311552);     //  barrier counter

  hipMemsetAsync(CNT, 0, 128, stream);
  mega_k<<<512, 256, 0, stream>>>(nodes, mask, wq, wkv, wo, bq, bkv, bo,
                                  XB, WQKVT, WOT, PM, Qm, Km, VTm, AOm, out, CNT);
}

// Round 6
// 325.616 us; speedup vs baseline: 1.2187x; 1.2187x over previous
//
#include <hip/hip_runtime.h>
#include <cstdint>
#include <cstddef>

#define DEVI __device__ __forceinline__

typedef __bf16 bf16x8 __attribute__((ext_vector_type(8)));
typedef float floatx4 __attribute__((ext_vector_type(4)));
typedef unsigned short us4v __attribute__((ext_vector_type(4)));
typedef unsigned short us8 __attribute__((ext_vector_type(8)));

static_assert(sizeof(bf16x8) == 16, "bf16x8 must be 16B");
static_assert(sizeof(us8) == 16, "us8 must be 16B");

// ---------------- helpers ----------------

#if __has_builtin(__builtin_amdgcn_cvt_pk_bf16_f32)
DEVI unsigned short f2bf(float f) {
  typedef __bf16 bf16x2 __attribute__((ext_vector_type(2)));
  union { bf16x2 v; unsigned short u[2]; } c;
  c.v = __builtin_amdgcn_cvt_pk_bf16_f32(f, 0.f);
  return c.u[0];
}
#else
DEVI unsigned short f2bf(float f) {
  unsigned int u = __float_as_uint(f);
  u += 0x7fffu + ((u >> 16) & 1u);   // RNE
  return (unsigned short)(u >> 16);
}
#endif

DEVI float exp2c(float x) {
#if __has_builtin(__builtin_amdgcn_exp2f)
  return __builtin_amdgcn_exp2f(x);
#else
  return exp2f(x);
#endif
}

DEVI bf16x8 ld8(const unsigned short* p) { return *(const bf16x8*)p; }

typedef const __attribute__((address_space(1))) void* gas_ptr;
typedef __attribute__((address_space(3))) void* las_ptr;

DEVI void gld16(const void* g, void* l) {
  __builtin_amdgcn_global_load_lds((gas_ptr)g, (las_ptr)l, 16, 0, 0);
}

#define WAIT_LGKM0() __builtin_amdgcn_s_waitcnt(0xc07f)   // lgkmcnt(0) only
#define WAIT_VM12()  __builtin_amdgcn_s_waitcnt(0x0f7c)   // vmcnt(12) only
#define WAIT_VM0()   __builtin_amdgcn_s_waitcnt(0x0f70)   // vmcnt(0) only
#define SB()         __builtin_amdgcn_sched_barrier(0)

// ---- hand-rolled grid barrier, R6: relaxed polls, fences only at edges ----
// R5 post-mortem: ACQUIRE per poll emits buffer_inv -> L2-invalidate storm
// (~1e5 invs) -> everything L3-latency-bound (330us @ 3% busy). Fix: scope
// (AGENT) keeps the atomic coherent (sc1 bypass); ordering moves to TWO
// __threadfence() calls: release-side wbl2 before arrive, acquire-side inv
// once on exit. ~3 coherence ops per block total instead of per poll.
DEVI void grid_bar(unsigned int* cnt, unsigned int target, int tid) {
  __syncthreads();
  if (tid == 0) {
    __threadfence();   // release: flush this block's global writes
    __hip_atomic_fetch_add(cnt, 1u, __ATOMIC_RELAXED, __HIP_MEMORY_SCOPE_AGENT);
    while (__hip_atomic_load(cnt, __ATOMIC_RELAXED, __HIP_MEMORY_SCOPE_AGENT) < target)
      __builtin_amdgcn_s_sleep(32);
    __threadfence();   // acquire: invalidate stale caches once
  }
  __syncthreads();     // all waves of block proceed after fences
}

// ================= fused persistent kernel (plain launch + own barrier) =================
// grid = 512 blocks x 256 threads, 2 blocks/CU (LDS 66.5 KB).
// Phase 0: prep (mask pack / cvt / weight transpose), 10624 units grid-strided.
// Phase 1: QKV GEMM, 768 64x128 tiles grid-strided.
// Phase 2: flash attention, 512 units (identity map) -- pins grid shape.
// Phase 3: out GEMM, 256 64x128 tiles on blocks 0..255.
__global__ __launch_bounds__(256, 2) void mega_k(
    const float* __restrict__ nodes, const void* __restrict__ mask,
    const float* __restrict__ wq, const float* __restrict__ wkv,
    const float* __restrict__ wo,
    const float* __restrict__ bq, const float* __restrict__ bkv,
    const float* __restrict__ bo,
    unsigned short* __restrict__ XB, unsigned short* __restrict__ WQKVT,
    unsigned short* __restrict__ WOT, unsigned int* __restrict__ pm,
    unsigned short* __restrict__ Qm, unsigned short* __restrict__ Km,
    unsigned short* __restrict__ VTm, unsigned short* __restrict__ AOm,
    float* __restrict__ out, unsigned int* __restrict__ gcnt) {
  __shared__ alignas(16) char smU[66560];    // 64 KB main + 1 KB aux + pad
  const int blk = blockIdx.x;
  const int tid = threadIdx.x;
  const int wave = tid >> 6, lane = tid & 63, quad = lane >> 4, l16 = lane & 15;

  // ---------------- phase 0: prep ----------------
  {
    int* modeP = (int*)(smU + 65536);
    unsigned short* t2 = (unsigned short*)smU;   // 8 KB
    for (int bid = blk; bid < 10624; bid += 512) {
      __syncthreads();                           // protect LDS reuse across units
      if (bid < 8192) {
        // ---- mask pack: thread handles 4 elems; 8 threads -> one 32-bit word ----
        const unsigned int* md = (const unsigned int*)mask;
        unsigned int probe = md[tid];
        bool odd = (probe > 1u && probe != 0x3f800000u);
        if (tid == 0) *modeP = 0;
        __syncthreads();
        if (odd) atomicOr(modeP, 1);
        __syncthreads();
        int byteMode = *modeP;
        int t = bid * 256 + tid;
        unsigned int n;
        if (byteMode) {
          unsigned int x = md[t];
          n = ((x & 0xffu) ? 1u : 0u) | ((x & 0xff00u) ? 2u : 0u) |
              ((x & 0xff0000u) ? 4u : 0u) | ((x >> 24) ? 8u : 0u);
        } else {
          uint4 v = ((const uint4*)mask)[t];
          n = (v.x ? 1u : 0u) | (v.y ? 2u : 0u) | (v.z ? 4u : 0u) | (v.w ? 8u : 0u);
        }
        unsigned int w = n << ((lane & 7) * 4);
        w |= __shfl_xor(w, 1);
        w |= __shfl_xor(w, 2);
        w |= __shfl_xor(w, 4);
        if ((lane & 7) == 0) pm[t >> 3] = w;
      } else if (bid < 10240) {
        // ---- nodes fp32 -> bf16 ----
        int i = (bid - 8192) * 256 + tid;
        float4 v = ((const float4*)nodes)[i];
        us4v o;
        o[0] = f2bf(v.x); o[1] = f2bf(v.y); o[2] = f2bf(v.z); o[3] = f2bf(v.w);
        *(us4v*)(XB + (size_t)i * 4) = o;
      } else {
        // ---- weight transpose fp32 [512][C] -> bf16 dst[(c0+c)*512+k] ----
        int tb = bid - 10240;
        int x = tb & 15, y = (tb >> 4) & 7, z = tb >> 7;
        const float* src; unsigned short* dst; int C, c0;
        bool active = true;
        if (z == 0)      { if (x >= 8) active = false; src = wq;  dst = WQKVT; C = 512;  c0 = 0; }
        else if (z == 1) { src = wkv; dst = WQKVT; C = 1024; c0 = 512; }
        else             { if (x >= 8) active = false; src = wo;  dst = WOT;  C = 512;  c0 = 0; }
        if (active) {                            // block-uniform condition
          const int t = tid;
          const int ct = x * 64, rt = y * 64;
          for (int p = 0; p < 4; p++) {
            int kl = p * 16 + (t >> 4);
            int cc = (t & 15) * 4;
            float4 v = *(const float4*)&src[(size_t)(rt + kl) * C + ct + cc];
            float f[4] = {v.x, v.y, v.z, v.w};
            for (int i = 0; i < 4; i++) {
              int c = cc + i;
              t2[c * 64 + (kl ^ (c & 56))] = f2bf(f[i]);
            }
          }
          __syncthreads();
          for (int p = 0; p < 2; p++) {
            int c = p * 32 + (t >> 3);
            int kc = (t & 7) * 8;
            us8 v = *(const us8*)&t2[c * 64 + (kc ^ (c & 56))];
            *(us8*)&dst[(size_t)(c0 + ct + c) * 512 + rt + kc] = v;
          }
        }
      }
    }
  }
  grid_bar(gcnt, 512, tid);

  // ---------------- phase 1: QKV GEMM (64x128 tiles, 768 grid-strided) ----------------
  {
    unsigned short* smem = (unsigned short*)smU;   // 16 KB
    unsigned short* sA = smem;
    unsigned short* sB = smem + 2048;
    const int wm = wave >> 1, wn = wave & 1;
    const int arow = lane >> 2;
    const int ag = lane & 3;
    for (int t = blk; t < 768; t += 512) {
      const int bm = t & 63, bn = t >> 6;
      floatx4 acc[2][4] = {};
      for (int kt = 0; kt < 16; kt++) {
        __syncthreads();
        {
          int rowA = wave * 16 + arow;
          int gA = ag ^ (rowA & 3);
          gld16(&XB[(size_t)(bm * 64 + rowA) * 512 + kt * 32 + gA * 8], &sA[(wave * 16) * 32]);
          for (int p = 0; p < 2; p++) {
            int rowB = p * 64 + wave * 16 + arow;
            int gB = ag ^ (rowB & 3);
            gld16(&WQKVT[(size_t)(bn * 128 + rowB) * 512 + kt * 32 + gB * 8],
                  &sB[(p * 64 + wave * 16) * 32]);
          }
        }
        __syncthreads();
        bf16x8 aF[2], bF[4];
        int swz = (quad ^ (l16 & 3)) * 8;
        for (int i = 0; i < 2; i++) aF[i] = ld8(&sA[(wm * 32 + i * 16 + l16) * 32 + swz]);
        for (int j = 0; j < 4; j++) bF[j] = ld8(&sB[(wn * 64 + j * 16 + l16) * 32 + swz]);
        for (int i = 0; i < 2; i++)
          for (int j = 0; j < 4; j++)
            acc[i][j] = __builtin_amdgcn_mfma_f32_16x16x32_bf16(aF[i], bF[j], acc[i][j], 0, 0, 0);
      }

      const int sec = bn * 2 + wn;               // 0..23: Q heads 0-7, K 8-15, V 16-23
      float bias[4];
      float scale = 1.0f;
      if (sec < 8) {
        for (int j = 0; j < 4; j++) bias[j] = bq[sec * 64 + j * 16 + l16];
        scale = 0.18033688011112042f;            // 0.125 * log2(e)
      } else {
        for (int j = 0; j < 4; j++) bias[j] = bkv[(sec - 8) * 64 + j * 16 + l16];
      }
      const int gr0 = bm * 64 + wm * 32;
      const int b = gr0 >> 11, n0 = gr0 & 2047;
      unsigned short* pw = smem + wave * 2048;
      __syncthreads();
      if (sec < 16) {
        for (int i = 0; i < 2; i++)
          for (int j = 0; j < 4; j++) {
            int cg2 = j * 2 + (l16 >> 3), ci = l16 & 7;
            for (int r = 0; r < 4; r++) {
              int row = i * 16 + quad * 4 + r;
              pw[row * 64 + ((cg2 ^ (row & 7)) * 8) + ci] = f2bf((acc[i][j][r] + bias[j]) * scale);
            }
          }
        WAIT_LGKM0();
        unsigned short* dst = (sec < 8) ? Qm + ((size_t)(b * 8 + sec) * 2048 + n0) * 64
                                        : Km + ((size_t)(b * 8 + sec - 8) * 2048 + n0) * 64;
        for (int p = 0; p < 4; p++) {
          int row = p * 8 + (lane >> 3);
          int c8 = lane & 7;
          us8 v = *(const us8*)&pw[row * 64 + ((c8 ^ (row & 7)) * 8)];
          *(us8*)&dst[(size_t)row * 64 + c8 * 8] = v;
        }
      } else {
        // V: [64 d][32 n] s-permuted; local n = i*16 + quad*4 + r -> s = quad*8 + i*4 + r
        for (int i = 0; i < 2; i++)
          for (int j = 0; j < 4; j++) {
            int d = j * 16 + l16;
            us4v tv;
            for (int r = 0; r < 4; r++) tv[r] = f2bf(acc[i][j][r] + bias[j]);
            *(us4v*)&pw[d * 32 + ((quad ^ (d & 3)) * 8) + i * 4] = tv;
          }
        WAIT_LGKM0();
        unsigned short* dst = VTm + (size_t)(b * 8 + sec - 16) * 64 * 2048 + n0;
        for (int p = 0; p < 4; p++) {
          int d = p * 16 + (lane >> 2);
          int c4 = lane & 3;
          us8 v = *(const us8*)&pw[d * 32 + ((c4 ^ (d & 3)) * 8)];
          *(us8*)&dst[(size_t)d * 2048 + c4 * 8] = v;
        }
      }
    }
  }
  grid_bar(gcnt, 1024, tid);

  // ---------------- phase 2: flash attention (identity map, 512 units) ----------------
  {
    // per (buf, wave): [0,2048) K tile [32 keys][64 d], [2048,4096) V tile [64 d][32 s]
    unsigned short (*kv)[4][4096] = (unsigned short (*)[4][4096])smU;   // 64 KB
    float (*lsumB)[64] = (float (*)[64])(smU + 65536);                  // 1 KB
    const int bh = blk & 15, qt = blk >> 4, b = bh >> 3, h = bh & 7;
    const int q0 = qt * 64;
    const unsigned short* Qb = Qm + (size_t)bh * 2048 * 64;
    const unsigned short* Kb = Km + (size_t)bh * 2048 * 64;
    const unsigned short* Vb = VTm + (size_t)bh * 64 * 2048;
    const unsigned int* pmB = pm + (size_t)b * 2048 * 64;

    bf16x8 qF[4][2];
#pragma unroll
    for (int qb = 0; qb < 4; qb++) {
      qF[qb][0] = ld8(&Qb[(size_t)(q0 + qb * 16 + l16) * 64 + quad * 8]);
      qF[qb][1] = ld8(&Qb[(size_t)(q0 + qb * 16 + l16) * 64 + 32 + quad * 8]);
    }

    floatx4 oacc[4][4] = {};                   // [db][qb]
    floatx4 lsacc[4] = {};                     // ones-MFMA row sums, [qb]

    union { us8 u; bf16x8 v; } onesU;
#pragma unroll
    for (int i = 0; i < 8; i++) onesU.u[i] = 0x3f80;   // bf16 1.0
    const bf16x8 onesF = onesU.v;

    const int srow = lane >> 3;                // K staging: row-in-8
    const int gK = (lane & 7) ^ srow;          // K source d-group (3-bit XOR)
    const int dV = lane >> 2;                  // V staging: d-row-in-16
    const int gV = (lane & 3) ^ (dV & 3);      // V source s-group (2-bit XOR)
    const int rsw0 = quad ^ (l16 & 7);
    const int rsw1 = (4 + quad) ^ (l16 & 7);

    unsigned short* kv0 = &kv[0][wave][0];
    unsigned short* kv1 = &kv[1][wave][0];

    struct MW { unsigned int w[4]; };
    MW mwA, mwB;

    auto prefetch = [&](int it, unsigned short* dst, MW& mw) {
      const int k0w = it * 128 + wave * 32;
#pragma unroll
      for (int qb = 0; qb < 4; qb++)
        mw.w[qb] = pmB[(size_t)(q0 + qb * 16 + l16) * 64 + it * 4 + wave];
#pragma unroll
      for (int p = 0; p < 4; p++) {
        gld16(&Kb[(size_t)(k0w + p * 8 + srow) * 64 + gK * 8], dst + p * 512);
        gld16(&Vb[(size_t)(p * 16 + dV) * 2048 + k0w + gV * 8], dst + 2048 + p * 512);
      }
    };

    auto step = [&](const unsigned short* buf, const MW& mw) {
      floatx4 st[4][2];
      __builtin_amdgcn_s_setprio(1);
#pragma unroll
      for (int k2 = 0; k2 < 2; k2++) {
        const unsigned short* kr = &buf[(k2 * 16 + l16) * 64];
        bf16x8 kf0 = ld8(kr + rsw0 * 8);
        bf16x8 kf1 = ld8(kr + rsw1 * 8);
#pragma unroll
        for (int qb = 0; qb < 4; qb++) {
          floatx4 z = {0.f, 0.f, 0.f, 0.f};
          z = __builtin_amdgcn_mfma_f32_16x16x32_bf16(kf0, qF[qb][0], z, 0, 0, 0);
          st[qb][k2] = __builtin_amdgcn_mfma_f32_16x16x32_bf16(kf1, qF[qb][1], z, 0, 0, 0);
        }
      }
      __builtin_amdgcn_s_setprio(0);
      union uB { bf16x8 v; unsigned short u[8]; } pf[4];
#pragma unroll
      for (int qb = 0; qb < 4; qb++) {
        unsigned int w = mw.w[qb];
#pragma unroll
        for (int k2 = 0; k2 < 2; k2++) {
#pragma unroll
          for (int r = 0; r < 4; r++) {
            float e = exp2c(st[qb][k2][r]);
            e = ((w >> (k2 * 16 + quad * 4 + r)) & 1u) ? e : 0.f;
            pf[qb].u[k2 * 4 + r] = f2bf(e);
          }
        }
      }
      __builtin_amdgcn_s_setprio(1);
#pragma unroll
      for (int qb = 0; qb < 4; qb++)
        lsacc[qb] = __builtin_amdgcn_mfma_f32_16x16x32_bf16(onesF, pf[qb].v, lsacc[qb], 0, 0, 0);
#pragma unroll
      for (int db = 0; db < 4; db++) {
        const int d = db * 16 + l16;
        bf16x8 va = ld8(&buf[2048 + d * 32 + ((quad ^ (d & 3)) * 8)]);
#pragma unroll
        for (int qb = 0; qb < 4; qb++)
          oacc[db][qb] =
              __builtin_amdgcn_mfma_f32_16x16x32_bf16(va, pf[qb].v, oacc[db][qb], 0, 0, 0);
      }
      __builtin_amdgcn_s_setprio(0);
    };

    SB();
    prefetch(0, kv0, mwA);
    SB();
#pragma unroll 1
    for (int i = 0; i < 8; ++i) {
      prefetch(i * 2 + 1, kv1, mwB);
      SB();
      WAIT_VM12();
      SB();
      step(kv0, mwA);
      SB();
      if (i < 7) {
        prefetch(i * 2 + 2, kv0, mwA);
        SB();
        WAIT_VM12();
        SB();
      } else {
        WAIT_VM0();
        SB();
      }
      step(kv1, mwB);
      SB();
    }

    if (quad == 0) {
#pragma unroll
      for (int qb = 0; qb < 4; qb++) lsumB[wave][qb * 16 + l16] = lsacc[qb][0];
    }
    __syncthreads();                           // all waves done with kv buffers

    float* pO = (float*)smU;                   // 64 KB = 4 regions x 16 KB
    float* myR = pO + wave * 4096;
#pragma unroll
    for (int db = 0; db < 4; db++)
#pragma unroll
      for (int qb = 0; qb < 4; qb++) {
        int q = qb * 16 + l16;
        *(floatx4*)&myR[q * 64 + (((db * 4 + quad) ^ l16) & 15) * 4] = oacc[db][qb];
      }
    __syncthreads();
    {
      int q = tid >> 2, dblk = tid & 3;
      float inv = 1.0f / (lsumB[0][q] + lsumB[1][q] + lsumB[2][q] + lsumB[3][q]);
      float o[16];
      for (int i = 0; i < 4; i++) {
        int dg = dblk * 4 + i;
        int off = q * 64 + ((dg ^ q) & 15) * 4;
        floatx4 s = *(floatx4*)&pO[off];
        s += *(floatx4*)&pO[4096 + off];
        s += *(floatx4*)&pO[8192 + off];
        s += *(floatx4*)&pO[12288 + off];
        for (int r = 0; r < 4; r++) o[i * 4 + r] = s[r] * inv;
      }
      us8 v0, v1;
      for (int i = 0; i < 8; i++) { v0[i] = f2bf(o[i]); v1[i] = f2bf(o[8 + i]); }
      unsigned short* dst = &AOm[((size_t)b * 2048 + q0 + q) * 512 + h * 64 + dblk * 16];
      *(us8*)dst = v0;
      *(us8*)(dst + 8) = v1;
    }
  }
  grid_bar(gcnt, 1536, tid);

  // ---------------- phase 3: out GEMM (64x128 tiles, blocks 0..255) ----------------
  if (blk < 256) {
    unsigned short* smem = (unsigned short*)smU;   // 12 KB
    unsigned short* sA = smem;
    unsigned short* sB = smem + 2048;
    const int wm = wave >> 1, wn = wave & 1;
    const int bm = blk & 63, bn = blk >> 6;
    floatx4 acc[2][4] = {};
    const int arow = lane >> 2;
    const int ag = lane & 3;
    for (int kt = 0; kt < 16; kt++) {
      __syncthreads();
      {
        int rowA = wave * 16 + arow;
        int gA = ag ^ (rowA & 3);
        gld16(&AOm[(size_t)(bm * 64 + rowA) * 512 + kt * 32 + gA * 8], &sA[(wave * 16) * 32]);
        for (int p = 0; p < 2; p++) {
          int rowB = p * 64 + wave * 16 + arow;
          int gB = ag ^ (rowB & 3);
          gld16(&WOT[(size_t)(bn * 128 + rowB) * 512 + kt * 32 + gB * 8],
                &sB[(p * 64 + wave * 16) * 32]);
        }
      }
      __syncthreads();
      bf16x8 aF[2], bF[4];
      int swz = (quad ^ (l16 & 3)) * 8;
      for (int i = 0; i < 2; i++) aF[i] = ld8(&sA[(wm * 32 + i * 16 + l16) * 32 + swz]);
      for (int j = 0; j < 4; j++) bF[j] = ld8(&sB[(wn * 64 + j * 16 + l16) * 32 + swz]);
      for (int i = 0; i < 2; i++)
        for (int j = 0; j < 4; j++)
          acc[i][j] = __builtin_amdgcn_mfma_f32_16x16x32_bf16(aF[i], bF[j], acc[i][j], 0, 0, 0);
    }
    for (int i = 0; i < 2; i++)
      for (int j = 0; j < 4; j++) {
        int gc = bn * 128 + wn * 64 + j * 16 + l16;
        float bb = bo[gc];
        for (int r = 0; r < 4; r++) {
          int gr = bm * 64 + wm * 32 + i * 16 + quad * 4 + r;
          out[(size_t)gr * 512 + gc] = acc[i][j][r] + bb;
        }
      }
  }
}

// ---------------- launch ----------------
extern "C" void kernel_launch(void* const* d_in, const int* in_sizes, int n_in,
                              void* d_out, int out_size, void* d_ws, size_t ws_size,
                              hipStream_t stream) {
  const float* nodes = (const float*)d_in[0];
  const void*  mask  = d_in[1];
  const float* wq    = (const float*)d_in[2];
  const float* bq    = (const float*)d_in[3];
  const float* wkv   = (const float*)d_in[4];
  const float* bkv   = (const float*)d_in[5];
  const float* wo    = (const float*)d_in[6];
  const float* bo    = (const float*)d_in[7];
  float* out = (float*)d_out;

  char* ws = (char*)d_ws;
  unsigned short* XB    = (unsigned short*)(ws + 0);          //  4 MB  bf16 nodes
  unsigned short* WQKVT = (unsigned short*)(ws + 4194304);    //  1.5MB
  unsigned short* WOT   = (unsigned short*)(ws + 5767168);    //  0.5MB
  unsigned short* Qm    = (unsigned short*)(ws + 6291456);    //  4 MB  [16][2048][64]
  unsigned short* Km    = (unsigned short*)(ws + 10485760);   //  4 MB
  unsigned short* VTm   = (unsigned short*)(ws + 18874368);   //  4 MB  [16][64][2048] s-perm
  unsigned short* AOm   = (unsigned short*)(ws + 23068672);   //  4 MB  [4096][512]
  unsigned int*   PM    = (unsigned int*)(ws + 27262976);     //  1 MB  packed mask
  unsigned int*   CNT   = (unsigned int*)(ws + 28311552);     //  barrier counter

  hipMemsetAsync(CNT, 0, 128, stream);
  mega_k<<<512, 256, 0, stream>>>(nodes, mask, wq, wkv, wo, bq, bkv, bo,
                                  XB, WQKVT, WOT, PM, Qm, Km, VTm, AOm, out, CNT);
}